// Round 17
// baseline (192.738 us; speedup 1.0000x reference)
//
#include <hip/hip_runtime.h>
#include <math.h>

// ---------------- types / helpers ----------------
typedef float f32x4 __attribute__((ext_vector_type(4)));
typedef __bf16 bf16x4 __attribute__((ext_vector_type(4)));
typedef __bf16 bf16x8 __attribute__((ext_vector_type(8)));

union FragU { bf16x8 v; bf16x4 h[2]; };

__device__ __forceinline__ unsigned short f2bf(float x) {
  union { float f; unsigned u; } un; un.f = x;
  unsigned r = un.u + 0x7FFFu + ((un.u >> 16) & 1u);
  return (unsigned short)(r >> 16);
}
__device__ __forceinline__ float bf2f(unsigned short h) {
  union { unsigned u; float f; } un; un.u = ((unsigned)h) << 16;
  return un.f;
}

// async global->LDS, 16 B per lane; dest = wave-uniform base + lane*16
__device__ __forceinline__ void gl16(const unsigned short* g, unsigned short* l) {
  __builtin_amdgcn_global_load_lds(
      (const __attribute__((address_space(1))) void*)g,
      (__attribute__((address_space(3))) void*)l, 16, 0, 0);
}

#define MROWS 50688   // 512 windows * 99 tokens
#define XTOK  50176   // 2*8*56*56 spatial tokens
#define GT_OFF 9633792
#define PLANE 1622016 // 50688*32 — plane stride for head-major qkv/attn-out layouts
#define SCALE_Q 0.17677669529663687f

// ---------------- fused prep: weights + mask table + rpb table ----------------
// blocks [0,1728): fp32->bf16 transposed weights
//   layout: qkvwT[576][192] @0 | projwT[192][192] @110592 | fc1wT[768][192] @147456 | fc2wT[192][768] @294912
// blocks [1728,1984): maskP[w256][base 16][t 4][r 99] u32 packed transposed mask
// blocks [1984,2133): rpbP[head][base 16][t 4][r 99] u32 packed transposed rpb
__global__ __launch_bounds__(256) void prep_all(
    const float* __restrict__ qkvw, const float* __restrict__ projw,
    const float* __restrict__ fc1w, const float* __restrict__ fc2w,
    const float* __restrict__ amask, const float* __restrict__ rpb,
    unsigned short* __restrict__ wout,
    unsigned int* __restrict__ maskP, unsigned int* __restrict__ rpbP)
{
  __shared__ float M[98][99];            // maskT transpose buffer (stride 99: conflict-free)
  const int tid = threadIdx.x;
  const int blk = blockIdx.x;
  if (blk < 1728) {
    int idx = blk * 256 + tid;
    float v;
    if (idx < 110592)      { int n = idx / 192, k = idx - n * 192; v = qkvw[k * 576 + n]; }
    else if (idx < 147456) { int j = idx - 110592; int n = j / 192, k = j - n * 192; v = projw[k * 192 + n]; }
    else if (idx < 294912) { int j = idx - 147456; int n = j / 192, k = j - n * 192; v = fc1w[k * 768 + n]; }
    else                   { int j = idx - 294912; int n = j / 768, k = j - n * 768; v = fc2w[k * 192 + n]; }
    wout[idx] = f2bf(v);
  } else if (blk < 1984) {
    const int w256 = blk - 1728;
    const float* src = amask + (size_t)w256 * 9604;
    for (int i = tid; i < 9604; i += 256) {
      int ti = i / 98, tj = i - ti * 98;
      M[ti][tj] = src[i];
    }
    __syncthreads();
    unsigned int* dst = maskP + (size_t)w256 * 6336;
    for (int o = tid; o < 6336; o += 256) {
      int base = o / 396, rem = o - base * 396;
      int t = rem / 99, r = rem - t * 99;
      int c0 = base + 32 * t;
      unsigned int res = 0;
      #pragma unroll
      for (int h = 0; h < 2; h++) {
        int c = c0 + 16 * h;
        float v = 0.0f;
        if (r >= 1 && c >= 1 && c <= 98) v = M[r - 1][c - 1];
        res |= ((unsigned int)f2bf(v)) << (16 * h);
      }
      dst[o] = res;
    }
  } else {
    int idx = (blk - 1984) * 256 + tid;
    if (idx >= 38016) return;            // 6 * 6336
    int head = idx / 6336, o = idx - head * 6336;
    int base = o / 396, rem = o - base * 396;
    int t = rem / 99, r = rem - t * 99;
    int c0 = base + 32 * t;
    unsigned int res = 0;
    #pragma unroll
    for (int h = 0; h < 2; h++) {
      int c = c0 + 16 * h;
      float v = 0.0f;
      if (r >= 1 && c >= 1 && c <= 98) {
        int ti = r - 1, tj = c - 1;
        int tdi = ti / 49, ri = ti - tdi * 49, thi = ri / 7, twi = ri - thi * 7;
        int tdj = tj / 49, rj = tj - tdj * 49, thj = rj / 7, twj = rj - thj * 7;
        int rel = (tdi - tdj + 1) * 169 + (thi - thj + 6) * 13 + (twi - twj + 6);
        v = rpb[rel * 6 + head];
      }
      res |= ((unsigned int)f2bf(v)) << (16 * h);
    }
    rpbP[idx] = res;
  }
}

// ---------------- LN1 + shift + window partition + global-token concat ----------------
__global__ __launch_bounds__(256) void ln1_kernel(
    const float* __restrict__ x, const float* __restrict__ gtok,
    const float* __restrict__ lw, const float* __restrict__ lb,
    unsigned short* __restrict__ out) // [50688][192] bf16
{
  int row = blockIdx.x * 4 + (threadIdx.x >> 6);
  int lane = threadIdx.x & 63;
  int win = row / 99, t = row - win * 99;
  size_t obase = (size_t)row * 192;
  if (t == 0) {
    const float* src = gtok + (size_t)win * 192;
    out[obase + lane]       = f2bf(src[lane]);
    out[obase + lane + 64]  = f2bf(src[lane + 64]);
    out[obase + lane + 128] = f2bf(src[lane + 128]);
    return;
  }
  int b = win >> 8, wi = win & 255;
  int wd = wi >> 6, wh = (wi >> 3) & 7, ww = wi & 7;
  int tt = t - 1, td = tt / 49, rr = tt - td * 49, th = rr / 7, tw = rr - th * 7;
  int d = (wd * 2 + td + 1) & 7;
  int h = wh * 7 + th + 3; if (h >= 56) h -= 56;
  int wc = ww * 7 + tw + 3; if (wc >= 56) wc -= 56;
  const float* src = x + ((size_t)(((b * 8 + d) * 56 + h) * 56 + wc)) * 192;
  float v0 = src[lane], v1 = src[lane + 64], v2 = src[lane + 128];
  float s = v0 + v1 + v2;
  float ss = v0 * v0 + v1 * v1 + v2 * v2;
  #pragma unroll
  for (int off = 32; off; off >>= 1) { s += __shfl_xor(s, off); ss += __shfl_xor(ss, off); }
  float mean = s * (1.0f / 192.0f);
  float var = ss * (1.0f / 192.0f) - mean * mean;
  float rstd = rsqrtf(var + 1e-5f);
  out[obase + lane]       = f2bf((v0 - mean) * rstd * lw[lane]       + lb[lane]);
  out[obase + lane + 64]  = f2bf((v1 - mean) * rstd * lw[lane + 64]  + lb[lane + 64]);
  out[obase + lane + 128] = f2bf((v2 - mean) * rstd * lw[lane + 128] + lb[lane + 128]);
}

// ---------------- LN2 (rows = x1 tokens then gt) ----------------
__global__ __launch_bounds__(256) void ln2_kernel(
    const float* __restrict__ resbuf,
    const float* __restrict__ lw, const float* __restrict__ lb,
    unsigned short* __restrict__ out)
{
  int row = blockIdx.x * 4 + (threadIdx.x >> 6);
  int lane = threadIdx.x & 63;
  const float* src = resbuf + (size_t)row * 192;
  float v0 = src[lane], v1 = src[lane + 64], v2 = src[lane + 128];
  float s = v0 + v1 + v2;
  float ss = v0 * v0 + v1 * v1 + v2 * v2;
  #pragma unroll
  for (int off = 32; off; off >>= 1) { s += __shfl_xor(s, off); ss += __shfl_xor(ss, off); }
  float mean = s * (1.0f / 192.0f);
  float var = ss * (1.0f / 192.0f) - mean * mean;
  float rstd = rsqrtf(var + 1e-5f);
  size_t obase = (size_t)row * 192;
  out[obase + lane]       = f2bf((v0 - mean) * rstd * lw[lane]       + lb[lane]);
  out[obase + lane + 64]  = f2bf((v1 - mean) * rstd * lw[lane + 64]  + lb[lane + 64]);
  out[obase + lane + 128] = f2bf((v2 - mean) * rstd * lw[lane + 128] + lb[lane + 128]);
}

// ---------------- GEMM: C[M x N] = A[M x K](bf16) @ BT[N x K]^T(bf16), tile 128x64, 4 waves ----------------
// Round-16 body unchanged (191 us best: global_load_lds w16, XOR swizzle, XCD-chunked grid,
// plane-major qkv out / proj in, cheap GELU, unrolled K-loop).
// MODE 0: qkv (+bias, scale q, bf16)  1: proj (+bias, scatter+residual fp32)
// MODE 2: fc1 (+bias, GELU, bf16)     3: fc2 (+bias, +residual, fp32 out split)
template<int MODE, int KITERS>
__global__ __launch_bounds__(256) void gemm_tpl(
    const unsigned short* __restrict__ A,
    const unsigned short* __restrict__ BT,
    const float* __restrict__ bias,
    unsigned short* __restrict__ outb,
    const float* __restrict__ xin,
    float* __restrict__ resbuf,
    float* __restrict__ dout,
    int N, int NC, int NWG)
{
  constexpr int K = KITERS * 64;
  __shared__ unsigned short As[128 * 64];
  __shared__ unsigned short Bs[64 * 64];
  const int tid = threadIdx.x, lane = tid & 63, w = tid >> 6;
  const int wm = w >> 1, wn = w & 1;
  const int l15 = lane & 15, l4 = lane >> 4;
  const int sx = lane & 7;                 // read-side swizzle (r&7 == lane&7 for all frags)
  const int srow8 = lane >> 3;             // staging: row within 8-row chunk
  const int csrc = (lane & 7) ^ srow8;     // staging: pre-swizzled source 16B-chunk

  // bijective XCD-chunked swizzle (nwg may not divide by 8)
  const int L = blockIdx.x;
  const int xcd = L & 7, hi = L >> 3;
  const int q = NWG >> 3, rr = NWG & 7;
  const int wgid = (xcd < rr ? xcd * (q + 1) : rr * (q + 1) + (xcd - rr) * q) + hi;
  const int cb = wgid % NC, rb = wgid / NC;
  const int mbase = rb * 128, nbase = cb * 64;

  f32x4 acc[4][2] = {};

  #pragma unroll
  for (int t = 0; t < KITERS; t++) {
    const int kb = t * 64;
    #pragma unroll
    for (int i = 0; i < 4; i++) {
      int chunk = w * 4 + i;               // 0..15
      int row = mbase + chunk * 8 + srow8; // tile row
      if constexpr (MODE == 1) {
        int k0 = kb + csrc * 8;
        gl16(A + (size_t)(k0 >> 5) * PLANE + (size_t)row * 32 + (k0 & 31), As + chunk * 512);
      } else {
        gl16(A + (size_t)row * K + kb + csrc * 8, As + chunk * 512);
      }
    }
    #pragma unroll
    for (int i = 0; i < 2; i++) {
      int chunk = w * 2 + i;               // 0..7
      gl16(BT + (size_t)(nbase + chunk * 8 + srow8) * K + kb + csrc * 8, Bs + chunk * 512);
    }
    __syncthreads();                       // vmcnt(0) drain inserted by compiler

    #pragma unroll
    for (int ks = 0; ks < 2; ks++) {
      bf16x8 af[4], bfr[2];
      #pragma unroll
      for (int mi = 0; mi < 4; mi++) {
        int r = wm * 64 + mi * 16 + l15;
        af[mi] = *reinterpret_cast<const bf16x8*>(As + r * 64 + (((ks * 4 + l4) ^ sx) * 8));
      }
      #pragma unroll
      for (int nj = 0; nj < 2; nj++) {
        int c = wn * 32 + nj * 16 + l15;
        bfr[nj] = *reinterpret_cast<const bf16x8*>(Bs + c * 64 + (((ks * 4 + l4) ^ sx) * 8));
      }
      #pragma unroll
      for (int mi = 0; mi < 4; mi++)
        #pragma unroll
        for (int nj = 0; nj < 2; nj++)
          acc[mi][nj] = __builtin_amdgcn_mfma_f32_16x16x32_bf16(af[mi], bfr[nj], acc[mi][nj], 0, 0, 0);
    }
    if (t + 1 < KITERS) __syncthreads();
  }

  #pragma unroll
  for (int mi = 0; mi < 4; mi++)
    #pragma unroll
    for (int nj = 0; nj < 2; nj++)
      #pragma unroll
      for (int reg = 0; reg < 4; reg++) {
        int r = mbase + wm * 64 + mi * 16 + l4 * 4 + reg;
        int c = nbase + wn * 32 + nj * 16 + l15;
        float v = acc[mi][nj][reg] + bias[c];
        if constexpr (MODE == 0) {
          if (c < 192) v *= SCALE_Q;
          // plane-major: plane = c>>5 (= type*6+head), offset = c&31
          outb[(size_t)(c >> 5) * PLANE + (size_t)r * 32 + (c & 31)] = f2bf(v);
        } else if constexpr (MODE == 1) {
          int win = r / 99, t2 = r - win * 99;
          if (t2 == 0) {
            resbuf[(size_t)(XTOK + win) * 192 + c] = v;
          } else {
            int b = win >> 8, wi = win & 255;
            int wd = wi >> 6, wh = (wi >> 3) & 7, ww = wi & 7;
            int tt = t2 - 1, td = tt / 49, rr2 = tt - td * 49, th = rr2 / 7, tw = rr2 - th * 7;
            int d = (wd * 2 + td + 1) & 7;
            int h = wh * 7 + th + 3; if (h >= 56) h -= 56;
            int wc = ww * 7 + tw + 3; if (wc >= 56) wc -= 56;
            size_t idx = ((size_t)(((b * 8 + d) * 56 + h) * 56 + wc)) * 192 + c;
            resbuf[idx] = xin[idx] + v;
          }
        } else if constexpr (MODE == 2) {
          // tanh-form GELU: 0.5x(1+tanh(y)) == x * sigmoid(2y), 2y = c1*x + c3*x^3
          float p = v * (1.5957691216f + 0.0713548128f * v * v);
          float g = v * __builtin_amdgcn_rcpf(1.0f + __expf(-p));
          outb[(size_t)r * N + c] = f2bf(g);
        } else {
          v += resbuf[(size_t)r * 192 + c];
          if (r < XTOK) dout[(size_t)r * 192 + c] = v;
          else dout[GT_OFF + (size_t)(r - XTOK) * 192 + c] = v;
        }
      }
}

// ---------------- attention, swapped-operand (S^T = K@Q^T), P fully in-register ----------------
// qkv PLANE-major [18][50688][32]; out PLANE-major [6][50688][32].
// Round-16 body + ONE change: output staged through LDS (aliases Qs, dead after QK^T) then
// stored as contiguous int4 chunks (16 B/lane, 1 KB/instr) -> full 128-B sectors, no write
// amplification (was 80 MB for a 19.5 MB output).
__global__ __launch_bounds__(256, 5) void attn_kernel(
    const unsigned short* __restrict__ qkv,
    const unsigned int* __restrict__ maskP, // [256][6336] packed transposed mask
    const unsigned int* __restrict__ rpbP,  // [6][6336] packed transposed rpb
    unsigned short* __restrict__ out)
{
  const int win = blockIdx.x & 511;
  const int head = blockIdx.x >> 9;
  const int tid = threadIdx.x, lane = tid & 63, w = tid >> 6;
  const int l15 = lane & 15, l4 = (lane >> 4) & 3;

  __shared__ __align__(16) unsigned short Qs[128][40];
  __shared__ __align__(16) unsigned short Ks[128][40];
  __shared__ __align__(16) unsigned short VTs[32][136];
  unsigned short* Sout = &Qs[0][0];       // [128][32] staging, aliases Qs (4096 <= 5120 shorts)

  const size_t rowbase = (size_t)win * 99;

  // ---- extra-table register preload (issued before staging; consumed after QK^T) ----
  const unsigned int* mkb = maskP + (size_t)(win & 255) * 6336;
  const unsigned int* rpb_ = rpbP + (size_t)head * 6336;
  const int q0 = w * 16 + l15;            // < 64, always valid
  const int q1 = 64 + q0;
  const int r1 = q1 < 99 ? q1 : 0;        // clamp padding rows
  unsigned int mk0[4][4], mk1[4][4], rp0[4][4], rp1[4][4];
  #pragma unroll
  for (int reg = 0; reg < 4; reg++)
    #pragma unroll
    for (int t = 0; t < 4; t++) {
      int boff = ((l4 * 4 + reg) * 4 + t) * 99;
      mk0[reg][t] = mkb[boff + q0];
      mk1[reg][t] = mkb[boff + r1];
      rp0[reg][t] = rpb_[boff + q0];
      rp1[reg][t] = rpb_[boff + r1];
    }

  // ---- stage Q, K (row-major in LDS) and V (transposed); contiguous plane reads ----
  const unsigned short* qkvQ = qkv + (size_t)head * PLANE + rowbase * 32;
  const unsigned short* qkvK = qkv + (size_t)(6 + head) * PLANE + rowbase * 32;
  const unsigned short* qkvV = qkv + (size_t)(12 + head) * PLANE + rowbase * 32;
  for (int idx = tid; idx < 512; idx += 256) {
    int r = idx >> 2, seg = (idx & 3) * 8;
    int4 zq = {0,0,0,0}, zk = {0,0,0,0}, zv = {0,0,0,0};
    if (r < 99) {
      zq = *reinterpret_cast<const int4*>(qkvQ + r * 32 + seg);
      zk = *reinterpret_cast<const int4*>(qkvK + r * 32 + seg);
      zv = *reinterpret_cast<const int4*>(qkvV + r * 32 + seg);
    }
    *reinterpret_cast<int4*>(&Qs[r][seg]) = zq;
    *reinterpret_cast<int4*>(&Ks[r][seg]) = zk;
    const unsigned short* pv = reinterpret_cast<const unsigned short*>(&zv);
    #pragma unroll
    for (int j = 0; j < 8; j++) VTs[seg + j][r] = pv[j];
  }
  __syncthreads();

  f32x4 oacc[2][2] = {};

  #pragma unroll
  for (int qi = 0; qi < 2; qi++) {
    const int qrow = qi * 64 + w * 16 + l15;
    FragU qf;
    qf.h[0] = *reinterpret_cast<const bf16x4*>(&Qs[qrow][l4 * 4]);
    qf.h[1] = *reinterpret_cast<const bf16x4*>(&Qs[qrow][16 + l4 * 4]);

    // S^T tiles: nj = k-token tile (k = nj*16 + l4*4 + reg); tile 7 (k>=112) always masked -> skipped
    f32x4 sacc[7] = {};
    #pragma unroll
    for (int nj = 0; nj < 7; nj++) {
      FragU kf;
      kf.h[0] = *reinterpret_cast<const bf16x4*>(&Ks[nj * 16 + l15][l4 * 4]);
      kf.h[1] = *reinterpret_cast<const bf16x4*>(&Ks[nj * 16 + l15][16 + l4 * 4]);
      sacc[nj] = __builtin_amdgcn_mfma_f32_16x16x32_bf16(kf.v, qf.v, sacc[nj], 0, 0, 0);
    }

    // ---- softmax fully in-register (row q = l15; k spread over l4 x reg x nj) ----
    float m = -1e30f;
    #pragma unroll
    for (int nj = 0; nj < 7; nj++) {
      int t = nj >> 1;
      #pragma unroll
      for (int reg = 0; reg < 4; reg++) {
        unsigned int mu = qi ? mk1[reg][t] : mk0[reg][t];
        unsigned int ru = qi ? rp1[reg][t] : rp0[reg][t];
        unsigned int mb = (nj & 1) ? (mu & 0xFFFF0000u) : (mu << 16);
        unsigned int rb = (nj & 1) ? (ru & 0xFFFF0000u) : (ru << 16);
        float s = sacc[nj][reg] + __uint_as_float(mb) + __uint_as_float(rb);
        if (nj == 6 && (96 + l4 * 4 + reg) >= 99) s = -1e30f;
        sacc[nj][reg] = s;
        m = fmaxf(m, s);
      }
    }
    m = fmaxf(m, __shfl_xor(m, 16));
    m = fmaxf(m, __shfl_xor(m, 32));
    float sum = 0.0f;
    #pragma unroll
    for (int nj = 0; nj < 7; nj++)
      #pragma unroll
      for (int reg = 0; reg < 4; reg++) {
        float e = __expf(sacc[nj][reg] - m);
        sacc[nj][reg] = e;
        sum += e;
      }
    sum += __shfl_xor(sum, 16);
    sum += __shfl_xor(sum, 32);
    const float inv = 1.0f / sum;

    // ---- PV: S^T acc layout == A-fragment layout, build pa in-lane ----
    #pragma unroll
    for (int ks = 0; ks < 4; ks++) {
      union { unsigned short u[8]; bf16x8 v; } pa;
      #pragma unroll
      for (int j = 0; j < 4; j++) {
        pa.u[j] = f2bf(sacc[2 * ks][j] * inv);
        pa.u[4 + j] = (ks == 3) ? (unsigned short)0 : f2bf(sacc[2 * ks + 1][j] * inv);
      }
      #pragma unroll
      for (int njd = 0; njd < 2; njd++) {
        FragU vb;
        vb.h[0] = *reinterpret_cast<const bf16x4*>(&VTs[njd * 16 + l15][ks * 32 + l4 * 4]);
        vb.h[1] = *reinterpret_cast<const bf16x4*>(&VTs[njd * 16 + l15][ks * 32 + 16 + l4 * 4]);
        oacc[qi][njd] = __builtin_amdgcn_mfma_f32_16x16x32_bf16(pa.v, vb.v, oacc[qi][njd], 0, 0, 0);
      }
    }
  }

  // ---- stage output in LDS (Qs dead), then contiguous int4 stores ----
  __syncthreads();                        // all waves done reading Qs/Ks/VTs
  #pragma unroll
  for (int qi = 0; qi < 2; qi++)
    #pragma unroll
    for (int njd = 0; njd < 2; njd++)
      #pragma unroll
      for (int reg = 0; reg < 4; reg++) {
        int qq = qi * 64 + w * 16 + l4 * 4 + reg;   // < 128
        Sout[qq * 32 + njd * 16 + l15] = f2bf(oacc[qi][njd][reg]);
      }
  __syncthreads();
  unsigned short* outp = out + (size_t)head * PLANE + rowbase * 32;
  for (int i = tid; i < 396; i += 256)    // 99 rows * 32 shorts = 396 int4
    *reinterpret_cast<int4*>(outp + i * 8) = *reinterpret_cast<const int4*>(Sout + i * 8);
}

// ---------------- host ----------------
extern "C" void kernel_launch(void* const* d_in, const int* in_sizes, int n_in,
                              void* d_out, int out_size, void* d_ws, size_t ws_size,
                              hipStream_t stream) {
  (void)in_sizes; (void)n_in; (void)out_size; (void)ws_size;
  const float* x     = (const float*)d_in[0];
  const float* gtok  = (const float*)d_in[1];
  // d_in[2] = position (unused by reference)
  const float* amask = (const float*)d_in[3];
  const float* n1w   = (const float*)d_in[4];
  const float* n1b   = (const float*)d_in[5];
  const float* qkvw  = (const float*)d_in[6];
  const float* qkvb  = (const float*)d_in[7];
  const float* projw = (const float*)d_in[8];
  const float* projb = (const float*)d_in[9];
  const float* rpb   = (const float*)d_in[10];
  const float* n2w   = (const float*)d_in[11];
  const float* n2b   = (const float*)d_in[12];
  const float* fc1w  = (const float*)d_in[13];
  const float* fc1b  = (const float*)d_in[14];
  const float* fc2w  = (const float*)d_in[15];
  const float* fc2b  = (const float*)d_in[16];

  char* ws = (char*)d_ws;
  unsigned short* wbuf = (unsigned short*)ws;              // 442368 bf16 weights (transposed)
  unsigned short* X    = (unsigned short*)(ws + 884736);   // 50688x192 bf16 (ln1 out row-major; attn out plane-major; ln2 out row-major)
  unsigned short* Qb   = (unsigned short*)(ws + 20348928); // qkv plane-major [18][50688][32]; then 50688x768 bf16 h
  float*          Rb   = (float*)(ws + 98205696);          // 50688x192 fp32 (x1 tokens + gt rows)
  unsigned int*   maskP= (unsigned int*)(ws + 98205696);   // 256x6336 u32 — aliases Rb (dead before MODE1)
  unsigned int*   rpbP = (unsigned int*)(ws + 104693760);  // 6x6336 u32  — aliases Rb (dead before MODE1)
  float* dout = (float*)d_out;

  prep_all<<<2133, 256, 0, stream>>>(qkvw, projw, fc1w, fc2w, amask, rpb, wbuf, maskP, rpbP);
  ln1_kernel<<<12672, 256, 0, stream>>>(x, gtok, n1w, n1b, X);
  gemm_tpl<0, 3><<<3564, 256, 0, stream>>>(X, wbuf, qkvb, Qb, nullptr, nullptr, nullptr, 576, 9, 3564);
  attn_kernel<<<3072, 256, 0, stream>>>(Qb, maskP, rpbP, X);
  gemm_tpl<1, 3><<<1188, 256, 0, stream>>>(X, wbuf + 110592, projb, nullptr, x, Rb, nullptr, 192, 3, 1188);
  ln2_kernel<<<12672, 256, 0, stream>>>(Rb, n2w, n2b, X);
  gemm_tpl<2, 3><<<4752, 256, 0, stream>>>(X, wbuf + 147456, fc1b, Qb, nullptr, nullptr, nullptr, 768, 12, 4752);
  gemm_tpl<3, 12><<<1188, 256, 0, stream>>>(Qb, wbuf + 294912, fc2b, nullptr, nullptr, Rb, dout, 192, 3, 1188);
}

// Round 18
// 176.829 us; speedup vs baseline: 1.0900x; 1.0900x over previous
//
#include <hip/hip_runtime.h>
#include <math.h>

// ---------------- types / helpers ----------------
typedef float f32x4 __attribute__((ext_vector_type(4)));
typedef __bf16 bf16x4 __attribute__((ext_vector_type(4)));
typedef __bf16 bf16x8 __attribute__((ext_vector_type(8)));

union FragU { bf16x8 v; bf16x4 h[2]; };

__device__ __forceinline__ unsigned short f2bf(float x) {
  union { __bf16 b; unsigned short u; } c; c.b = (__bf16)x; return c.u;  // HW cvt, RNE
}
__device__ __forceinline__ float bf2f(unsigned short h) {
  union { unsigned u; float f; } un; un.u = ((unsigned)h) << 16;
  return un.f;
}

// async global->LDS, 16 B per lane; dest = wave-uniform base + lane*16
__device__ __forceinline__ void gl16(const unsigned short* g, unsigned short* l) {
  __builtin_amdgcn_global_load_lds(
      (const __attribute__((address_space(1))) void*)g,
      (__attribute__((address_space(3))) void*)l, 16, 0, 0);
}

#define MROWS 50688   // 512 windows * 99 tokens
#define XTOK  50176   // 2*8*56*56 spatial tokens
#define GT_OFF 9633792
#define PLANE 1622016 // 50688*32 — plane stride for head-major qkv/attn-out layouts
#define SCALE_Q 0.17677669529663687f

// ---------------- fused prep: weights + mask table + rpb table ----------------
__global__ __launch_bounds__(256) void prep_all(
    const float* __restrict__ qkvw, const float* __restrict__ projw,
    const float* __restrict__ fc1w, const float* __restrict__ fc2w,
    const float* __restrict__ amask, const float* __restrict__ rpb,
    unsigned short* __restrict__ wout,
    unsigned int* __restrict__ maskP, unsigned int* __restrict__ rpbP)
{
  __shared__ float M[98][99];            // maskT transpose buffer (stride 99: conflict-free)
  const int tid = threadIdx.x;
  const int blk = blockIdx.x;
  if (blk < 1728) {
    int idx = blk * 256 + tid;
    float v;
    if (idx < 110592)      { int n = idx / 192, k = idx - n * 192; v = qkvw[k * 576 + n]; }
    else if (idx < 147456) { int j = idx - 110592; int n = j / 192, k = j - n * 192; v = projw[k * 192 + n]; }
    else if (idx < 294912) { int j = idx - 147456; int n = j / 192, k = j - n * 192; v = fc1w[k * 768 + n]; }
    else                   { int j = idx - 294912; int n = j / 768, k = j - n * 768; v = fc2w[k * 192 + n]; }
    wout[idx] = f2bf(v);
  } else if (blk < 1984) {
    const int w256 = blk - 1728;
    const float* src = amask + (size_t)w256 * 9604;
    for (int i = tid; i < 9604; i += 256) {
      int ti = i / 98, tj = i - ti * 98;
      M[ti][tj] = src[i];
    }
    __syncthreads();
    unsigned int* dst = maskP + (size_t)w256 * 6336;
    for (int o = tid; o < 6336; o += 256) {
      int base = o / 396, rem = o - base * 396;
      int t = rem / 99, r = rem - t * 99;
      int c0 = base + 32 * t;
      unsigned int res = 0;
      #pragma unroll
      for (int h = 0; h < 2; h++) {
        int c = c0 + 16 * h;
        float v = 0.0f;
        if (r >= 1 && c >= 1 && c <= 98) v = M[r - 1][c - 1];
        res |= ((unsigned int)f2bf(v)) << (16 * h);
      }
      dst[o] = res;
    }
  } else {
    int idx = (blk - 1984) * 256 + tid;
    if (idx >= 38016) return;            // 6 * 6336
    int head = idx / 6336, o = idx - head * 6336;
    int base = o / 396, rem = o - base * 396;
    int t = rem / 99, r = rem - t * 99;
    int c0 = base + 32 * t;
    unsigned int res = 0;
    #pragma unroll
    for (int h = 0; h < 2; h++) {
      int c = c0 + 16 * h;
      float v = 0.0f;
      if (r >= 1 && c >= 1 && c <= 98) {
        int ti = r - 1, tj = c - 1;
        int tdi = ti / 49, ri = ti - tdi * 49, thi = ri / 7, twi = ri - thi * 7;
        int tdj = tj / 49, rj = tj - tdj * 49, thj = rj / 7, twj = rj - thj * 7;
        int rel = (tdi - tdj + 1) * 169 + (thi - thj + 6) * 13 + (twi - twj + 6);
        v = rpb[rel * 6 + head];
      }
      res |= ((unsigned int)f2bf(v)) << (16 * h);
    }
    rpbP[idx] = res;
  }
}

// ---------------- LN1 + shift + window partition + global-token concat ----------------
__global__ __launch_bounds__(256) void ln1_kernel(
    const float* __restrict__ x, const float* __restrict__ gtok,
    const float* __restrict__ lw, const float* __restrict__ lb,
    unsigned short* __restrict__ out) // [50688][192] bf16
{
  int row = blockIdx.x * 4 + (threadIdx.x >> 6);
  int lane = threadIdx.x & 63;
  int win = row / 99, t = row - win * 99;
  size_t obase = (size_t)row * 192;
  if (t == 0) {
    const float* src = gtok + (size_t)win * 192;
    out[obase + lane]       = f2bf(src[lane]);
    out[obase + lane + 64]  = f2bf(src[lane + 64]);
    out[obase + lane + 128] = f2bf(src[lane + 128]);
    return;
  }
  int b = win >> 8, wi = win & 255;
  int wd = wi >> 6, wh = (wi >> 3) & 7, ww = wi & 7;
  int tt = t - 1, td = tt / 49, rr = tt - td * 49, th = rr / 7, tw = rr - th * 7;
  int d = (wd * 2 + td + 1) & 7;
  int h = wh * 7 + th + 3; if (h >= 56) h -= 56;
  int wc = ww * 7 + tw + 3; if (wc >= 56) wc -= 56;
  const float* src = x + ((size_t)(((b * 8 + d) * 56 + h) * 56 + wc)) * 192;
  float v0 = src[lane], v1 = src[lane + 64], v2 = src[lane + 128];
  float s = v0 + v1 + v2;
  float ss = v0 * v0 + v1 * v1 + v2 * v2;
  #pragma unroll
  for (int off = 32; off; off >>= 1) { s += __shfl_xor(s, off); ss += __shfl_xor(ss, off); }
  float mean = s * (1.0f / 192.0f);
  float var = ss * (1.0f / 192.0f) - mean * mean;
  float rstd = rsqrtf(var + 1e-5f);
  out[obase + lane]       = f2bf((v0 - mean) * rstd * lw[lane]       + lb[lane]);
  out[obase + lane + 64]  = f2bf((v1 - mean) * rstd * lw[lane + 64]  + lb[lane + 64]);
  out[obase + lane + 128] = f2bf((v2 - mean) * rstd * lw[lane + 128] + lb[lane + 128]);
}

// ---------------- LN2 (rows = x1 tokens then gt) ----------------
__global__ __launch_bounds__(256) void ln2_kernel(
    const float* __restrict__ resbuf,
    const float* __restrict__ lw, const float* __restrict__ lb,
    unsigned short* __restrict__ out)
{
  int row = blockIdx.x * 4 + (threadIdx.x >> 6);
  int lane = threadIdx.x & 63;
  const float* src = resbuf + (size_t)row * 192;
  float v0 = src[lane], v1 = src[lane + 64], v2 = src[lane + 128];
  float s = v0 + v1 + v2;
  float ss = v0 * v0 + v1 * v1 + v2 * v2;
  #pragma unroll
  for (int off = 32; off; off >>= 1) { s += __shfl_xor(s, off); ss += __shfl_xor(ss, off); }
  float mean = s * (1.0f / 192.0f);
  float var = ss * (1.0f / 192.0f) - mean * mean;
  float rstd = rsqrtf(var + 1e-5f);
  size_t obase = (size_t)row * 192;
  out[obase + lane]       = f2bf((v0 - mean) * rstd * lw[lane]       + lb[lane]);
  out[obase + lane + 64]  = f2bf((v1 - mean) * rstd * lw[lane + 64]  + lb[lane + 64]);
  out[obase + lane + 128] = f2bf((v2 - mean) * rstd * lw[lane + 128] + lb[lane + 128]);
}

// ---------------- GEMM: C[M x N] = A[M x K](bf16) @ BT[N x K]^T(bf16), tile 128x64, 4 waves ----------------
// Round-16 body (191 us best) unchanged except native-cvt f2bf.
// MODE 0: qkv (+bias, scale q, bf16, plane-major out)  1: proj (plane-major in, scatter+residual fp32)
// MODE 2: fc1 (+bias, GELU, bf16)                      3: fc2 (+bias, +residual, fp32 out split)
template<int MODE, int KITERS>
__global__ __launch_bounds__(256) void gemm_tpl(
    const unsigned short* __restrict__ A,
    const unsigned short* __restrict__ BT,
    const float* __restrict__ bias,
    unsigned short* __restrict__ outb,
    const float* __restrict__ xin,
    float* __restrict__ resbuf,
    float* __restrict__ dout,
    int N, int NC, int NWG)
{
  constexpr int K = KITERS * 64;
  __shared__ unsigned short As[128 * 64];
  __shared__ unsigned short Bs[64 * 64];
  const int tid = threadIdx.x, lane = tid & 63, w = tid >> 6;
  const int wm = w >> 1, wn = w & 1;
  const int l15 = lane & 15, l4 = lane >> 4;
  const int sx = lane & 7;                 // read-side swizzle (r&7 == lane&7 for all frags)
  const int srow8 = lane >> 3;             // staging: row within 8-row chunk
  const int csrc = (lane & 7) ^ srow8;     // staging: pre-swizzled source 16B-chunk

  // bijective XCD-chunked swizzle (nwg may not divide by 8)
  const int L = blockIdx.x;
  const int xcd = L & 7, hi = L >> 3;
  const int q = NWG >> 3, rr = NWG & 7;
  const int wgid = (xcd < rr ? xcd * (q + 1) : rr * (q + 1) + (xcd - rr) * q) + hi;
  const int cb = wgid % NC, rb = wgid / NC;
  const int mbase = rb * 128, nbase = cb * 64;

  f32x4 acc[4][2] = {};

  #pragma unroll
  for (int t = 0; t < KITERS; t++) {
    const int kb = t * 64;
    #pragma unroll
    for (int i = 0; i < 4; i++) {
      int chunk = w * 4 + i;               // 0..15
      int row = mbase + chunk * 8 + srow8; // tile row
      if constexpr (MODE == 1) {
        int k0 = kb + csrc * 8;
        gl16(A + (size_t)(k0 >> 5) * PLANE + (size_t)row * 32 + (k0 & 31), As + chunk * 512);
      } else {
        gl16(A + (size_t)row * K + kb + csrc * 8, As + chunk * 512);
      }
    }
    #pragma unroll
    for (int i = 0; i < 2; i++) {
      int chunk = w * 2 + i;               // 0..7
      gl16(BT + (size_t)(nbase + chunk * 8 + srow8) * K + kb + csrc * 8, Bs + chunk * 512);
    }
    __syncthreads();                       // vmcnt(0) drain inserted by compiler

    #pragma unroll
    for (int ks = 0; ks < 2; ks++) {
      bf16x8 af[4], bfr[2];
      #pragma unroll
      for (int mi = 0; mi < 4; mi++) {
        int r = wm * 64 + mi * 16 + l15;
        af[mi] = *reinterpret_cast<const bf16x8*>(As + r * 64 + (((ks * 4 + l4) ^ sx) * 8));
      }
      #pragma unroll
      for (int nj = 0; nj < 2; nj++) {
        int c = wn * 32 + nj * 16 + l15;
        bfr[nj] = *reinterpret_cast<const bf16x8*>(Bs + c * 64 + (((ks * 4 + l4) ^ sx) * 8));
      }
      #pragma unroll
      for (int mi = 0; mi < 4; mi++)
        #pragma unroll
        for (int nj = 0; nj < 2; nj++)
          acc[mi][nj] = __builtin_amdgcn_mfma_f32_16x16x32_bf16(af[mi], bfr[nj], acc[mi][nj], 0, 0, 0);
    }
    if (t + 1 < KITERS) __syncthreads();
  }

  #pragma unroll
  for (int mi = 0; mi < 4; mi++)
    #pragma unroll
    for (int nj = 0; nj < 2; nj++)
      #pragma unroll
      for (int reg = 0; reg < 4; reg++) {
        int r = mbase + wm * 64 + mi * 16 + l4 * 4 + reg;
        int c = nbase + wn * 32 + nj * 16 + l15;
        float v = acc[mi][nj][reg] + bias[c];
        if constexpr (MODE == 0) {
          if (c < 192) v *= SCALE_Q;
          // plane-major: plane = c>>5 (= type*6+head), offset = c&31
          outb[(size_t)(c >> 5) * PLANE + (size_t)r * 32 + (c & 31)] = f2bf(v);
        } else if constexpr (MODE == 1) {
          int win = r / 99, t2 = r - win * 99;
          if (t2 == 0) {
            resbuf[(size_t)(XTOK + win) * 192 + c] = v;
          } else {
            int b = win >> 8, wi = win & 255;
            int wd = wi >> 6, wh = (wi >> 3) & 7, ww = wi & 7;
            int tt = t2 - 1, td = tt / 49, rr2 = tt - td * 49, th = rr2 / 7, tw = rr2 - th * 7;
            int d = (wd * 2 + td + 1) & 7;
            int h = wh * 7 + th + 3; if (h >= 56) h -= 56;
            int wc = ww * 7 + tw + 3; if (wc >= 56) wc -= 56;
            size_t idx = ((size_t)(((b * 8 + d) * 56 + h) * 56 + wc)) * 192 + c;
            resbuf[idx] = xin[idx] + v;
          }
        } else if constexpr (MODE == 2) {
          // tanh-form GELU: 0.5x(1+tanh(y)) == x * sigmoid(2y), 2y = c1*x + c3*x^3
          float p = v * (1.5957691216f + 0.0713548128f * v * v);
          float g = v * __builtin_amdgcn_rcpf(1.0f + __expf(-p));
          outb[(size_t)r * N + c] = f2bf(g);
        } else {
          v += resbuf[(size_t)r * 192 + c];
          if (r < XTOK) dout[(size_t)r * 192 + c] = v;
          else dout[GT_OFF + (size_t)(r - XTOK) * 192 + c] = v;
        }
      }
}

// ---------------- attention, swapped-operand (S^T = K@Q^T), P fully in-register ----------------
// qkv PLANE-major [18][50688][32]; out PLANE-major [6][50688][32]. Round-16 store path
// (direct plane-major, r17 staging reverted). New: setprio around MFMA clusters (T5),
// VTs stride 140 (280-B rows, 8-B aligned; V read conflicts 4-way -> <=2-way).
__global__ __launch_bounds__(256, 5) void attn_kernel(
    const unsigned short* __restrict__ qkv,
    const unsigned int* __restrict__ maskP, // [256][6336] packed transposed mask
    const unsigned int* __restrict__ rpbP,  // [6][6336] packed transposed rpb
    unsigned short* __restrict__ out)
{
  const int win = blockIdx.x & 511;
  const int head = blockIdx.x >> 9;
  const int tid = threadIdx.x, lane = tid & 63, w = tid >> 6;
  const int l15 = lane & 15, l4 = (lane >> 4) & 3;

  __shared__ __align__(16) unsigned short Qs[128][40];
  __shared__ __align__(16) unsigned short Ks[128][40];
  __shared__ __align__(16) unsigned short VTs[32][140];

  const size_t rowbase = (size_t)win * 99;

  // ---- extra-table register preload (issued before staging; consumed after QK^T) ----
  const unsigned int* mkb = maskP + (size_t)(win & 255) * 6336;
  const unsigned int* rpb_ = rpbP + (size_t)head * 6336;
  const int q0 = w * 16 + l15;            // < 64, always valid
  const int q1 = 64 + q0;
  const int r1 = q1 < 99 ? q1 : 0;        // clamp padding rows
  unsigned int mk0[4][4], mk1[4][4], rp0[4][4], rp1[4][4];
  #pragma unroll
  for (int reg = 0; reg < 4; reg++)
    #pragma unroll
    for (int t = 0; t < 4; t++) {
      int boff = ((l4 * 4 + reg) * 4 + t) * 99;
      mk0[reg][t] = mkb[boff + q0];
      mk1[reg][t] = mkb[boff + r1];
      rp0[reg][t] = rpb_[boff + q0];
      rp1[reg][t] = rpb_[boff + r1];
    }

  // ---- stage Q, K (row-major in LDS) and V (transposed); contiguous plane reads ----
  const unsigned short* qkvQ = qkv + (size_t)head * PLANE + rowbase * 32;
  const unsigned short* qkvK = qkv + (size_t)(6 + head) * PLANE + rowbase * 32;
  const unsigned short* qkvV = qkv + (size_t)(12 + head) * PLANE + rowbase * 32;
  for (int idx = tid; idx < 512; idx += 256) {
    int r = idx >> 2, seg = (idx & 3) * 8;
    int4 zq = {0,0,0,0}, zk = {0,0,0,0}, zv = {0,0,0,0};
    if (r < 99) {
      zq = *reinterpret_cast<const int4*>(qkvQ + r * 32 + seg);
      zk = *reinterpret_cast<const int4*>(qkvK + r * 32 + seg);
      zv = *reinterpret_cast<const int4*>(qkvV + r * 32 + seg);
    }
    *reinterpret_cast<int4*>(&Qs[r][seg]) = zq;
    *reinterpret_cast<int4*>(&Ks[r][seg]) = zk;
    const unsigned short* pv = reinterpret_cast<const unsigned short*>(&zv);
    #pragma unroll
    for (int j = 0; j < 8; j++) VTs[seg + j][r] = pv[j];
  }
  __syncthreads();

  f32x4 oacc[2][2] = {};

  #pragma unroll
  for (int qi = 0; qi < 2; qi++) {
    const int qrow = qi * 64 + w * 16 + l15;
    FragU qf;
    qf.h[0] = *reinterpret_cast<const bf16x4*>(&Qs[qrow][l4 * 4]);
    qf.h[1] = *reinterpret_cast<const bf16x4*>(&Qs[qrow][16 + l4 * 4]);

    // S^T tiles: nj = k-token tile (k = nj*16 + l4*4 + reg); tile 7 (k>=112) always masked -> skipped
    f32x4 sacc[7] = {};
    __builtin_amdgcn_s_setprio(1);
    #pragma unroll
    for (int nj = 0; nj < 7; nj++) {
      FragU kf;
      kf.h[0] = *reinterpret_cast<const bf16x4*>(&Ks[nj * 16 + l15][l4 * 4]);
      kf.h[1] = *reinterpret_cast<const bf16x4*>(&Ks[nj * 16 + l15][16 + l4 * 4]);
      sacc[nj] = __builtin_amdgcn_mfma_f32_16x16x32_bf16(kf.v, qf.v, sacc[nj], 0, 0, 0);
    }
    __builtin_amdgcn_s_setprio(0);

    // ---- softmax fully in-register (row q = l15; k spread over l4 x reg x nj) ----
    float m = -1e30f;
    #pragma unroll
    for (int nj = 0; nj < 7; nj++) {
      int t = nj >> 1;
      #pragma unroll
      for (int reg = 0; reg < 4; reg++) {
        unsigned int mu = qi ? mk1[reg][t] : mk0[reg][t];
        unsigned int ru = qi ? rp1[reg][t] : rp0[reg][t];
        unsigned int mb = (nj & 1) ? (mu & 0xFFFF0000u) : (mu << 16);
        unsigned int rb = (nj & 1) ? (ru & 0xFFFF0000u) : (ru << 16);
        float s = sacc[nj][reg] + __uint_as_float(mb) + __uint_as_float(rb);
        if (nj == 6 && (96 + l4 * 4 + reg) >= 99) s = -1e30f;
        sacc[nj][reg] = s;
        m = fmaxf(m, s);
      }
    }
    m = fmaxf(m, __shfl_xor(m, 16));
    m = fmaxf(m, __shfl_xor(m, 32));
    float sum = 0.0f;
    #pragma unroll
    for (int nj = 0; nj < 7; nj++)
      #pragma unroll
      for (int reg = 0; reg < 4; reg++) {
        float e = __expf(sacc[nj][reg] - m);
        sacc[nj][reg] = e;
        sum += e;
      }
    sum += __shfl_xor(sum, 16);
    sum += __shfl_xor(sum, 32);
    const float inv = 1.0f / sum;

    // ---- PV: S^T acc layout == A-fragment layout, build pa in-lane ----
    #pragma unroll
    for (int ks = 0; ks < 4; ks++) {
      union { unsigned short u[8]; bf16x8 v; } pa;
      #pragma unroll
      for (int j = 0; j < 4; j++) {
        pa.u[j] = f2bf(sacc[2 * ks][j] * inv);
        pa.u[4 + j] = (ks == 3) ? (unsigned short)0 : f2bf(sacc[2 * ks + 1][j] * inv);
      }
      __builtin_amdgcn_s_setprio(1);
      #pragma unroll
      for (int njd = 0; njd < 2; njd++) {
        FragU vb;
        vb.h[0] = *reinterpret_cast<const bf16x4*>(&VTs[njd * 16 + l15][ks * 32 + l4 * 4]);
        vb.h[1] = *reinterpret_cast<const bf16x4*>(&VTs[njd * 16 + l15][ks * 32 + 16 + l4 * 4]);
        oacc[qi][njd] = __builtin_amdgcn_mfma_f32_16x16x32_bf16(pa.v, vb.v, oacc[qi][njd], 0, 0, 0);
      }
      __builtin_amdgcn_s_setprio(0);
    }
  }

  // ---- store plane-major: out[head][rowbase+q][njd*16+l15] ----
  unsigned short* outp = out + (size_t)head * PLANE;
  #pragma unroll
  for (int qi = 0; qi < 2; qi++)
    #pragma unroll
    for (int njd = 0; njd < 2; njd++)
      #pragma unroll
      for (int reg = 0; reg < 4; reg++) {
        int q = qi * 64 + w * 16 + l4 * 4 + reg;
        if (q < 99)
          outp[(rowbase + q) * 32 + njd * 16 + l15] = f2bf(oacc[qi][njd][reg]);
      }
}

// ---------------- host ----------------
extern "C" void kernel_launch(void* const* d_in, const int* in_sizes, int n_in,
                              void* d_out, int out_size, void* d_ws, size_t ws_size,
                              hipStream_t stream) {
  (void)in_sizes; (void)n_in; (void)out_size; (void)ws_size;
  const float* x     = (const float*)d_in[0];
  const float* gtok  = (const float*)d_in[1];
  // d_in[2] = position (unused by reference)
  const float* amask = (const float*)d_in[3];
  const float* n1w   = (const float*)d_in[4];
  const float* n1b   = (const float*)d_in[5];
  const float* qkvw  = (const float*)d_in[6];
  const float* qkvb  = (const float*)d_in[7];
  const float* projw = (const float*)d_in[8];
  const float* projb = (const float*)d_in[9];
  const float* rpb   = (const float*)d_in[10];
  const float* n2w   = (const float*)d_in[11];
  const float* n2b   = (const float*)d_in[12];
  const float* fc1w  = (const float*)d_in[13];
  const float* fc1b  = (const float*)d_in[14];
  const float* fc2w  = (const float*)d_in[15];
  const float* fc2b  = (const float*)d_in[16];

  char* ws = (char*)d_ws;
  unsigned short* wbuf = (unsigned short*)ws;              // 442368 bf16 weights (transposed)
  unsigned short* X    = (unsigned short*)(ws + 884736);   // 50688x192 bf16 (ln1 out row-major; attn out plane-major; ln2 out row-major)
  unsigned short* Qb   = (unsigned short*)(ws + 20348928); // qkv plane-major [18][50688][32]; then 50688x768 bf16 h
  float*          Rb   = (float*)(ws + 98205696);          // 50688x192 fp32 (x1 tokens + gt rows)
  unsigned int*   maskP= (unsigned int*)(ws + 98205696);   // 256x6336 u32 — aliases Rb (dead before MODE1)
  unsigned int*   rpbP = (unsigned int*)(ws + 104693760);  // 6x6336 u32  — aliases Rb (dead before MODE1)
  float* dout = (float*)d_out;

  prep_all<<<2133, 256, 0, stream>>>(qkvw, projw, fc1w, fc2w, amask, rpb, wbuf, maskP, rpbP);
  ln1_kernel<<<12672, 256, 0, stream>>>(x, gtok, n1w, n1b, X);
  gemm_tpl<0, 3><<<3564, 256, 0, stream>>>(X, wbuf, qkvb, Qb, nullptr, nullptr, nullptr, 576, 9, 3564);
  attn_kernel<<<3072, 256, 0, stream>>>(Qb, maskP, rpbP, X);
  gemm_tpl<1, 3><<<1188, 256, 0, stream>>>(X, wbuf + 110592, projb, nullptr, x, Rb, nullptr, 192, 3, 1188);
  ln2_kernel<<<12672, 256, 0, stream>>>(Rb, n2w, n2b, X);
  gemm_tpl<2, 3><<<4752, 256, 0, stream>>>(X, wbuf + 147456, fc1b, Qb, nullptr, nullptr, nullptr, 768, 12, 4752);
  gemm_tpl<3, 12><<<1188, 256, 0, stream>>>(Qb, wbuf + 294912, fc2b, nullptr, nullptr, Rb, dout, 192, 3, 1188);
}

// Round 20
// 174.750 us; speedup vs baseline: 1.1029x; 1.0119x over previous
//
#include <hip/hip_runtime.h>
#include <math.h>

// ---------------- types / helpers ----------------
typedef float f32x4 __attribute__((ext_vector_type(4)));
typedef __bf16 bf16x4 __attribute__((ext_vector_type(4)));
typedef __bf16 bf16x8 __attribute__((ext_vector_type(8)));

union FragU { bf16x8 v; bf16x4 h[2]; };

__device__ __forceinline__ unsigned short f2bf(float x) {
  union { __bf16 b; unsigned short u; } c; c.b = (__bf16)x; return c.u;  // HW cvt, RNE
}
__device__ __forceinline__ float bf2f(unsigned short h) {
  union { unsigned u; float f; } un; un.u = ((unsigned)h) << 16;
  return un.f;
}

// async global->LDS, 16 B per lane; dest = wave-uniform base + lane*16
__device__ __forceinline__ void gl16(const unsigned short* g, unsigned short* l) {
  __builtin_amdgcn_global_load_lds(
      (const __attribute__((address_space(1))) void*)g,
      (__attribute__((address_space(3))) void*)l, 16, 0, 0);
}

#define MROWS 50688   // 512 windows * 99 tokens
#define XTOK  50176   // 2*8*56*56 spatial tokens
#define GT_OFF 9633792
#define PLANE 1622016 // 50688*32 — plane stride for head-major qkv/attn-out layouts
#define SCALE_Q 0.17677669529663687f

// ---------------- fused prep: weights + mask table + rpb table ----------------
__global__ __launch_bounds__(256) void prep_all(
    const float* __restrict__ qkvw, const float* __restrict__ projw,
    const float* __restrict__ fc1w, const float* __restrict__ fc2w,
    const float* __restrict__ amask, const float* __restrict__ rpb,
    unsigned short* __restrict__ wout,
    unsigned int* __restrict__ maskP, unsigned int* __restrict__ rpbP)
{
  __shared__ float M[98][99];            // maskT transpose buffer (stride 99: conflict-free)
  const int tid = threadIdx.x;
  const int blk = blockIdx.x;
  if (blk < 1728) {
    int idx = blk * 256 + tid;
    float v;
    if (idx < 110592)      { int n = idx / 192, k = idx - n * 192; v = qkvw[k * 576 + n]; }
    else if (idx < 147456) { int j = idx - 110592; int n = j / 192, k = j - n * 192; v = projw[k * 192 + n]; }
    else if (idx < 294912) { int j = idx - 147456; int n = j / 192, k = j - n * 192; v = fc1w[k * 768 + n]; }
    else                   { int j = idx - 294912; int n = j / 768, k = j - n * 768; v = fc2w[k * 192 + n]; }
    wout[idx] = f2bf(v);
  } else if (blk < 1984) {
    const int w256 = blk - 1728;
    const float* src = amask + (size_t)w256 * 9604;
    for (int i = tid; i < 9604; i += 256) {
      int ti = i / 98, tj = i - ti * 98;
      M[ti][tj] = src[i];
    }
    __syncthreads();
    unsigned int* dst = maskP + (size_t)w256 * 6336;
    for (int o = tid; o < 6336; o += 256) {
      int base = o / 396, rem = o - base * 396;
      int t = rem / 99, r = rem - t * 99;
      int c0 = base + 32 * t;
      unsigned int res = 0;
      #pragma unroll
      for (int h = 0; h < 2; h++) {
        int c = c0 + 16 * h;
        float v = 0.0f;
        if (r >= 1 && c >= 1 && c <= 98) v = M[r - 1][c - 1];
        res |= ((unsigned int)f2bf(v)) << (16 * h);
      }
      dst[o] = res;
    }
  } else {
    int idx = (blk - 1984) * 256 + tid;
    if (idx >= 38016) return;            // 6 * 6336
    int head = idx / 6336, o = idx - head * 6336;
    int base = o / 396, rem = o - base * 396;
    int t = rem / 99, r = rem - t * 99;
    int c0 = base + 32 * t;
    unsigned int res = 0;
    #pragma unroll
    for (int h = 0; h < 2; h++) {
      int c = c0 + 16 * h;
      float v = 0.0f;
      if (r >= 1 && c >= 1 && c <= 98) {
        int ti = r - 1, tj = c - 1;
        int tdi = ti / 49, ri = ti - tdi * 49, thi = ri / 7, twi = ri - thi * 7;
        int tdj = tj / 49, rj = tj - tdj * 49, thj = rj / 7, twj = rj - thj * 7;
        int rel = (tdi - tdj + 1) * 169 + (thi - thj + 6) * 13 + (twi - twj + 6);
        v = rpb[rel * 6 + head];
      }
      res |= ((unsigned int)f2bf(v)) << (16 * h);
    }
    rpbP[idx] = res;
  }
}

// ---------------- LN1 + shift + window partition + global-token concat ----------------
__global__ __launch_bounds__(256) void ln1_kernel(
    const float* __restrict__ x, const float* __restrict__ gtok,
    const float* __restrict__ lw, const float* __restrict__ lb,
    unsigned short* __restrict__ out) // [50688][192] bf16
{
  int row = blockIdx.x * 4 + (threadIdx.x >> 6);
  int lane = threadIdx.x & 63;
  int win = row / 99, t = row - win * 99;
  size_t obase = (size_t)row * 192;
  if (t == 0) {
    const float* src = gtok + (size_t)win * 192;
    out[obase + lane]       = f2bf(src[lane]);
    out[obase + lane + 64]  = f2bf(src[lane + 64]);
    out[obase + lane + 128] = f2bf(src[lane + 128]);
    return;
  }
  int b = win >> 8, wi = win & 255;
  int wd = wi >> 6, wh = (wi >> 3) & 7, ww = wi & 7;
  int tt = t - 1, td = tt / 49, rr = tt - td * 49, th = rr / 7, tw = rr - th * 7;
  int d = (wd * 2 + td + 1) & 7;
  int h = wh * 7 + th + 3; if (h >= 56) h -= 56;
  int wc = ww * 7 + tw + 3; if (wc >= 56) wc -= 56;
  const float* src = x + ((size_t)(((b * 8 + d) * 56 + h) * 56 + wc)) * 192;
  float v0 = src[lane], v1 = src[lane + 64], v2 = src[lane + 128];
  float s = v0 + v1 + v2;
  float ss = v0 * v0 + v1 * v1 + v2 * v2;
  #pragma unroll
  for (int off = 32; off; off >>= 1) { s += __shfl_xor(s, off); ss += __shfl_xor(ss, off); }
  float mean = s * (1.0f / 192.0f);
  float var = ss * (1.0f / 192.0f) - mean * mean;
  float rstd = rsqrtf(var + 1e-5f);
  out[obase + lane]       = f2bf((v0 - mean) * rstd * lw[lane]       + lb[lane]);
  out[obase + lane + 64]  = f2bf((v1 - mean) * rstd * lw[lane + 64]  + lb[lane + 64]);
  out[obase + lane + 128] = f2bf((v2 - mean) * rstd * lw[lane + 128] + lb[lane + 128]);
}

// ---------------- LN2 (rows = x1 tokens then gt), bf16 residual input ----------------
__global__ __launch_bounds__(256) void ln2_kernel(
    const unsigned short* __restrict__ resbuf,
    const float* __restrict__ lw, const float* __restrict__ lb,
    unsigned short* __restrict__ out)
{
  int row = blockIdx.x * 4 + (threadIdx.x >> 6);
  int lane = threadIdx.x & 63;
  const unsigned short* src = resbuf + (size_t)row * 192;
  float v0 = bf2f(src[lane]), v1 = bf2f(src[lane + 64]), v2 = bf2f(src[lane + 128]);
  float s = v0 + v1 + v2;
  float ss = v0 * v0 + v1 * v1 + v2 * v2;
  #pragma unroll
  for (int off = 32; off; off >>= 1) { s += __shfl_xor(s, off); ss += __shfl_xor(ss, off); }
  float mean = s * (1.0f / 192.0f);
  float var = ss * (1.0f / 192.0f) - mean * mean;
  float rstd = rsqrtf(var + 1e-5f);
  size_t obase = (size_t)row * 192;
  out[obase + lane]       = f2bf((v0 - mean) * rstd * lw[lane]       + lb[lane]);
  out[obase + lane + 64]  = f2bf((v1 - mean) * rstd * lw[lane + 64]  + lb[lane + 64]);
  out[obase + lane + 128] = f2bf((v2 - mean) * rstd * lw[lane + 128] + lb[lane + 128]);
}

// ---------------- GEMM: C[M x N] = A[M x K](bf16) @ BT[N x K]^T(bf16), tile 128x64, 4 waves ----------------
// Round-18 body (176.8 us best). ONE change: residual buffer Rb is bf16 now —
// MODE 1 stores f2bf(x + proj), MODE 3 reads bf2f(residual). Halves Rb traffic (~58 MB saved).
// MODE 0: qkv (+bias, scale q, bf16, plane-major out)  1: proj (plane-major in, scatter+residual bf16)
// MODE 2: fc1 (+bias, GELU, bf16)                      3: fc2 (+bias, +residual, fp32 out split)
template<int MODE, int KITERS>
__global__ __launch_bounds__(256) void gemm_tpl(
    const unsigned short* __restrict__ A,
    const unsigned short* __restrict__ BT,
    const float* __restrict__ bias,
    unsigned short* __restrict__ outb,
    const float* __restrict__ xin,
    unsigned short* __restrict__ rbuf,
    float* __restrict__ dout,
    int N, int NC, int NWG)
{
  constexpr int K = KITERS * 64;
  __shared__ unsigned short As[128 * 64];
  __shared__ unsigned short Bs[64 * 64];
  const int tid = threadIdx.x, lane = tid & 63, w = tid >> 6;
  const int wm = w >> 1, wn = w & 1;
  const int l15 = lane & 15, l4 = lane >> 4;
  const int sx = lane & 7;                 // read-side swizzle (r&7 == lane&7 for all frags)
  const int srow8 = lane >> 3;             // staging: row within 8-row chunk
  const int csrc = (lane & 7) ^ srow8;     // staging: pre-swizzled source 16B-chunk

  // bijective XCD-chunked swizzle (nwg may not divide by 8)
  const int L = blockIdx.x;
  const int xcd = L & 7, hi = L >> 3;
  const int q = NWG >> 3, rr = NWG & 7;
  const int wgid = (xcd < rr ? xcd * (q + 1) : rr * (q + 1) + (xcd - rr) * q) + hi;
  const int cb = wgid % NC, rb = wgid / NC;
  const int mbase = rb * 128, nbase = cb * 64;

  f32x4 acc[4][2] = {};

  #pragma unroll
  for (int t = 0; t < KITERS; t++) {
    const int kb = t * 64;
    #pragma unroll
    for (int i = 0; i < 4; i++) {
      int chunk = w * 4 + i;               // 0..15
      int row = mbase + chunk * 8 + srow8; // tile row
      if constexpr (MODE == 1) {
        int k0 = kb + csrc * 8;
        gl16(A + (size_t)(k0 >> 5) * PLANE + (size_t)row * 32 + (k0 & 31), As + chunk * 512);
      } else {
        gl16(A + (size_t)row * K + kb + csrc * 8, As + chunk * 512);
      }
    }
    #pragma unroll
    for (int i = 0; i < 2; i++) {
      int chunk = w * 2 + i;               // 0..7
      gl16(BT + (size_t)(nbase + chunk * 8 + srow8) * K + kb + csrc * 8, Bs + chunk * 512);
    }
    __syncthreads();                       // vmcnt(0) drain inserted by compiler

    #pragma unroll
    for (int ks = 0; ks < 2; ks++) {
      bf16x8 af[4], bfr[2];
      #pragma unroll
      for (int mi = 0; mi < 4; mi++) {
        int r = wm * 64 + mi * 16 + l15;
        af[mi] = *reinterpret_cast<const bf16x8*>(As + r * 64 + (((ks * 4 + l4) ^ sx) * 8));
      }
      #pragma unroll
      for (int nj = 0; nj < 2; nj++) {
        int c = wn * 32 + nj * 16 + l15;
        bfr[nj] = *reinterpret_cast<const bf16x8*>(Bs + c * 64 + (((ks * 4 + l4) ^ sx) * 8));
      }
      #pragma unroll
      for (int mi = 0; mi < 4; mi++)
        #pragma unroll
        for (int nj = 0; nj < 2; nj++)
          acc[mi][nj] = __builtin_amdgcn_mfma_f32_16x16x32_bf16(af[mi], bfr[nj], acc[mi][nj], 0, 0, 0);
    }
    if (t + 1 < KITERS) __syncthreads();
  }

  #pragma unroll
  for (int mi = 0; mi < 4; mi++)
    #pragma unroll
    for (int nj = 0; nj < 2; nj++)
      #pragma unroll
      for (int reg = 0; reg < 4; reg++) {
        int r = mbase + wm * 64 + mi * 16 + l4 * 4 + reg;
        int c = nbase + wn * 32 + nj * 16 + l15;
        float v = acc[mi][nj][reg] + bias[c];
        if constexpr (MODE == 0) {
          if (c < 192) v *= SCALE_Q;
          // plane-major: plane = c>>5 (= type*6+head), offset = c&31
          outb[(size_t)(c >> 5) * PLANE + (size_t)r * 32 + (c & 31)] = f2bf(v);
        } else if constexpr (MODE == 1) {
          int win = r / 99, t2 = r - win * 99;
          if (t2 == 0) {
            rbuf[(size_t)(XTOK + win) * 192 + c] = f2bf(v);
          } else {
            int b = win >> 8, wi = win & 255;
            int wd = wi >> 6, wh = (wi >> 3) & 7, ww = wi & 7;
            int tt = t2 - 1, td = tt / 49, rr2 = tt - td * 49, th = rr2 / 7, tw = rr2 - th * 7;
            int d = (wd * 2 + td + 1) & 7;
            int h = wh * 7 + th + 3; if (h >= 56) h -= 56;
            int wc = ww * 7 + tw + 3; if (wc >= 56) wc -= 56;
            size_t idx = ((size_t)(((b * 8 + d) * 56 + h) * 56 + wc)) * 192 + c;
            rbuf[idx] = f2bf(xin[idx] + v);
          }
        } else if constexpr (MODE == 2) {
          // tanh-form GELU: 0.5x(1+tanh(y)) == x * sigmoid(2y), 2y = c1*x + c3*x^3
          float p = v * (1.5957691216f + 0.0713548128f * v * v);
          float g = v * __builtin_amdgcn_rcpf(1.0f + __expf(-p));
          outb[(size_t)r * N + c] = f2bf(g);
        } else {
          v += bf2f(rbuf[(size_t)r * 192 + c]);
          if (r < XTOK) dout[(size_t)r * 192 + c] = v;
          else dout[GT_OFF + (size_t)(r - XTOK) * 192 + c] = v;
        }
      }
}

// ---------------- attention, swapped-operand (S^T = K@Q^T), P fully in-register ----------------
// qkv PLANE-major [18][50688][32]; out PLANE-major [6][50688][32]. setprio around MFMA
// clusters (T5); VTs stride 140.
__global__ __launch_bounds__(256, 5) void attn_kernel(
    const unsigned short* __restrict__ qkv,
    const unsigned int* __restrict__ maskP, // [256][6336] packed transposed mask
    const unsigned int* __restrict__ rpbP,  // [6][6336] packed transposed rpb
    unsigned short* __restrict__ out)
{
  const int win = blockIdx.x & 511;
  const int head = blockIdx.x >> 9;
  const int tid = threadIdx.x, lane = tid & 63, w = tid >> 6;
  const int l15 = lane & 15, l4 = (lane >> 4) & 3;

  __shared__ __align__(16) unsigned short Qs[128][40];
  __shared__ __align__(16) unsigned short Ks[128][40];
  __shared__ __align__(16) unsigned short VTs[32][140];

  const size_t rowbase = (size_t)win * 99;

  // ---- extra-table register preload (issued before staging; consumed after QK^T) ----
  const unsigned int* mkb = maskP + (size_t)(win & 255) * 6336;
  const unsigned int* rpb_ = rpbP + (size_t)head * 6336;
  const int q0 = w * 16 + l15;            // < 64, always valid
  const int q1 = 64 + q0;
  const int r1 = q1 < 99 ? q1 : 0;        // clamp padding rows
  unsigned int mk0[4][4], mk1[4][4], rp0[4][4], rp1[4][4];
  #pragma unroll
  for (int reg = 0; reg < 4; reg++)
    #pragma unroll
    for (int t = 0; t < 4; t++) {
      int boff = ((l4 * 4 + reg) * 4 + t) * 99;
      mk0[reg][t] = mkb[boff + q0];
      mk1[reg][t] = mkb[boff + r1];
      rp0[reg][t] = rpb_[boff + q0];
      rp1[reg][t] = rpb_[boff + r1];
    }

  // ---- stage Q, K (row-major in LDS) and V (transposed); contiguous plane reads ----
  const unsigned short* qkvQ = qkv + (size_t)head * PLANE + rowbase * 32;
  const unsigned short* qkvK = qkv + (size_t)(6 + head) * PLANE + rowbase * 32;
  const unsigned short* qkvV = qkv + (size_t)(12 + head) * PLANE + rowbase * 32;
  for (int idx = tid; idx < 512; idx += 256) {
    int r = idx >> 2, seg = (idx & 3) * 8;
    int4 zq = {0,0,0,0}, zk = {0,0,0,0}, zv = {0,0,0,0};
    if (r < 99) {
      zq = *reinterpret_cast<const int4*>(qkvQ + r * 32 + seg);
      zk = *reinterpret_cast<const int4*>(qkvK + r * 32 + seg);
      zv = *reinterpret_cast<const int4*>(qkvV + r * 32 + seg);
    }
    *reinterpret_cast<int4*>(&Qs[r][seg]) = zq;
    *reinterpret_cast<int4*>(&Ks[r][seg]) = zk;
    const unsigned short* pv = reinterpret_cast<const unsigned short*>(&zv);
    #pragma unroll
    for (int j = 0; j < 8; j++) VTs[seg + j][r] = pv[j];
  }
  __syncthreads();

  f32x4 oacc[2][2] = {};

  #pragma unroll
  for (int qi = 0; qi < 2; qi++) {
    const int qrow = qi * 64 + w * 16 + l15;
    FragU qf;
    qf.h[0] = *reinterpret_cast<const bf16x4*>(&Qs[qrow][l4 * 4]);
    qf.h[1] = *reinterpret_cast<const bf16x4*>(&Qs[qrow][16 + l4 * 4]);

    // S^T tiles: nj = k-token tile (k = nj*16 + l4*4 + reg); tile 7 (k>=112) always masked -> skipped
    f32x4 sacc[7] = {};
    __builtin_amdgcn_s_setprio(1);
    #pragma unroll
    for (int nj = 0; nj < 7; nj++) {
      FragU kf;
      kf.h[0] = *reinterpret_cast<const bf16x4*>(&Ks[nj * 16 + l15][l4 * 4]);
      kf.h[1] = *reinterpret_cast<const bf16x4*>(&Ks[nj * 16 + l15][16 + l4 * 4]);
      sacc[nj] = __builtin_amdgcn_mfma_f32_16x16x32_bf16(kf.v, qf.v, sacc[nj], 0, 0, 0);
    }
    __builtin_amdgcn_s_setprio(0);

    // ---- softmax fully in-register (row q = l15; k spread over l4 x reg x nj) ----
    float m = -1e30f;
    #pragma unroll
    for (int nj = 0; nj < 7; nj++) {
      int t = nj >> 1;
      #pragma unroll
      for (int reg = 0; reg < 4; reg++) {
        unsigned int mu = qi ? mk1[reg][t] : mk0[reg][t];
        unsigned int ru = qi ? rp1[reg][t] : rp0[reg][t];
        unsigned int mb = (nj & 1) ? (mu & 0xFFFF0000u) : (mu << 16);
        unsigned int rb = (nj & 1) ? (ru & 0xFFFF0000u) : (ru << 16);
        float s = sacc[nj][reg] + __uint_as_float(mb) + __uint_as_float(rb);
        if (nj == 6 && (96 + l4 * 4 + reg) >= 99) s = -1e30f;
        sacc[nj][reg] = s;
        m = fmaxf(m, s);
      }
    }
    m = fmaxf(m, __shfl_xor(m, 16));
    m = fmaxf(m, __shfl_xor(m, 32));
    float sum = 0.0f;
    #pragma unroll
    for (int nj = 0; nj < 7; nj++)
      #pragma unroll
      for (int reg = 0; reg < 4; reg++) {
        float e = __expf(sacc[nj][reg] - m);
        sacc[nj][reg] = e;
        sum += e;
      }
    sum += __shfl_xor(sum, 16);
    sum += __shfl_xor(sum, 32);
    const float inv = 1.0f / sum;

    // ---- PV: S^T acc layout == A-fragment layout, build pa in-lane ----
    #pragma unroll
    for (int ks = 0; ks < 4; ks++) {
      union { unsigned short u[8]; bf16x8 v; } pa;
      #pragma unroll
      for (int j = 0; j < 4; j++) {
        pa.u[j] = f2bf(sacc[2 * ks][j] * inv);
        pa.u[4 + j] = (ks == 3) ? (unsigned short)0 : f2bf(sacc[2 * ks + 1][j] * inv);
      }
      __builtin_amdgcn_s_setprio(1);
      #pragma unroll
      for (int njd = 0; njd < 2; njd++) {
        FragU vb;
        vb.h[0] = *reinterpret_cast<const bf16x4*>(&VTs[njd * 16 + l15][ks * 32 + l4 * 4]);
        vb.h[1] = *reinterpret_cast<const bf16x4*>(&VTs[njd * 16 + l15][ks * 32 + 16 + l4 * 4]);
        oacc[qi][njd] = __builtin_amdgcn_mfma_f32_16x16x32_bf16(pa.v, vb.v, oacc[qi][njd], 0, 0, 0);
      }
      __builtin_amdgcn_s_setprio(0);
    }
  }

  // ---- store plane-major: out[head][rowbase+q][njd*16+l15] ----
  unsigned short* outp = out + (size_t)head * PLANE;
  #pragma unroll
  for (int qi = 0; qi < 2; qi++)
    #pragma unroll
    for (int njd = 0; njd < 2; njd++)
      #pragma unroll
      for (int reg = 0; reg < 4; reg++) {
        int q = qi * 64 + w * 16 + l4 * 4 + reg;
        if (q < 99)
          outp[(rowbase + q) * 32 + njd * 16 + l15] = f2bf(oacc[qi][njd][reg]);
      }
}

// ---------------- host ----------------
extern "C" void kernel_launch(void* const* d_in, const int* in_sizes, int n_in,
                              void* d_out, int out_size, void* d_ws, size_t ws_size,
                              hipStream_t stream) {
  (void)in_sizes; (void)n_in; (void)out_size; (void)ws_size;
  const float* x     = (const float*)d_in[0];
  const float* gtok  = (const float*)d_in[1];
  // d_in[2] = position (unused by reference)
  const float* amask = (const float*)d_in[3];
  const float* n1w   = (const float*)d_in[4];
  const float* n1b   = (const float*)d_in[5];
  const float* qkvw  = (const float*)d_in[6];
  const float* qkvb  = (const float*)d_in[7];
  const float* projw = (const float*)d_in[8];
  const float* projb = (const float*)d_in[9];
  const float* rpb   = (const float*)d_in[10];
  const float* n2w   = (const float*)d_in[11];
  const float* n2b   = (const float*)d_in[12];
  const float* fc1w  = (const float*)d_in[13];
  const float* fc1b  = (const float*)d_in[14];
  const float* fc2w  = (const float*)d_in[15];
  const float* fc2b  = (const float*)d_in[16];

  char* ws = (char*)d_ws;
  unsigned short* wbuf = (unsigned short*)ws;              // 442368 bf16 weights (transposed)
  unsigned short* X    = (unsigned short*)(ws + 884736);   // 50688x192 bf16 (ln1 out row-major; attn out plane-major; ln2 out row-major)
  unsigned short* Qb   = (unsigned short*)(ws + 20348928); // qkv plane-major [18][50688][32]; then 50688x768 bf16 h
  unsigned short* Rb   = (unsigned short*)(ws + 98205696); // 50688x192 bf16 residual (x1 tokens + gt rows)
  unsigned int*   maskP= (unsigned int*)(ws + 120000512);  // 256x6336 u32 (6.5 MB)
  unsigned int*   rpbP = (unsigned int*)(ws + 146488576);  // 6x6336 u32 (152 KB)
  float* dout = (float*)d_out;

  prep_all<<<2133, 256, 0, stream>>>(qkvw, projw, fc1w, fc2w, amask, rpb, wbuf, maskP, rpbP);
  ln1_kernel<<<12672, 256, 0, stream>>>(x, gtok, n1w, n1b, X);
  gemm_tpl<0, 3><<<3564, 256, 0, stream>>>(X, wbuf, qkvb, Qb, nullptr, nullptr, nullptr, 576, 9, 3564);
  attn_kernel<<<3072, 256, 0, stream>>>(Qb, maskP, rpbP, X);
  gemm_tpl<1, 3><<<1188, 256, 0, stream>>>(X, wbuf + 110592, projb, nullptr, x, Rb, nullptr, 192, 3, 1188);
  ln2_kernel<<<12672, 256, 0, stream>>>(Rb, n2w, n2b, X);
  gemm_tpl<2, 3><<<4752, 256, 0, stream>>>(X, wbuf + 147456, fc1b, Qb, nullptr, nullptr, nullptr, 768, 12, 4752);
  gemm_tpl<3, 12><<<1188, 256, 0, stream>>>(Qb, wbuf + 294912, fc2b, nullptr, nullptr, Rb, dout, 192, 3, 1188);
}